// Round 1
// baseline (195.618 us; speedup 1.0000x reference)
//
#include <hip/hip_runtime.h>
#include <math.h>

// FFT-based Toeplitz/circular convolution:
//   o[b,:,d] = IFFT( FFT(pad(x[b,:,d]),8192) * FFT(t[:,d],8192) ).real[:4096]
// b=4, n=4096, d=512, N=8192.
//
// Pipeline (fast path, needs 48 MB ws):
//   K0a: transpose x (b,n,d) -> xT (b,d,n)      [coalesced tile transpose]
//   K0b: transpose t (2n,d)  -> tT (d,2n)
//   K1 : per-(b,d) block: radix-4 DIF fwd FFT of t row (spectrum -> regs),
//        fwd FFT of padded x row, pointwise mul (digit-reversed order matches),
//        radix-4 DIT inverse -> natural order, write real part over xT row.
//   K2 : transpose xT (b,d,n) -> out (b,n,d)
// Slow path (ws too small): same K1 with strided global access, no transposes.

#define NFFT 8192
#define NTHR 512

__device__ __forceinline__ float2 cmul(float2 a, float2 b) {
    return make_float2(a.x * b.x - a.y * b.y, a.x * b.y + a.y * b.x);
}

// ---------- forward: 6x radix-4 DIF (L=8192..8) + final radix-2 ----------
__device__ void fwd_fft(float2* S, int tid) {
    for (int lL = 13; lL >= 3; lL -= 2) {
        const int L = 1 << lL;
        const int q = L >> 2;
        const float ang = -6.28318530717958647692f / (float)L;
        #pragma unroll
        for (int it = 0; it < 4; ++it) {
            int p = tid + (it << 9);            // [0, 2048)
            int m = p & (q - 1);
            int B = ((p >> (lL - 2)) << lL) + m;
            float2 a0 = S[B], a1 = S[B + q], a2 = S[B + 2 * q], a3 = S[B + 3 * q];
            float2 b0 = make_float2(a0.x + a2.x, a0.y + a2.y);
            float2 b1 = make_float2(a1.x + a3.x, a1.y + a3.y);
            float2 b2 = make_float2(a0.x - a2.x, a0.y - a2.y);
            float2 b3 = make_float2(a1.x - a3.x, a1.y - a3.y);
            float2 y0 = make_float2(b0.x + b1.x, b0.y + b1.y);
            float2 y2 = make_float2(b0.x - b1.x, b0.y - b1.y);
            float2 y1 = make_float2(b2.x + b3.y, b2.y - b3.x);  // b2 - i*b3
            float2 y3 = make_float2(b2.x - b3.y, b2.y + b3.x);  // b2 + i*b3
            float s1, c1;
            __sincosf(ang * (float)m, &s1, &c1);
            float2 w1 = make_float2(c1, s1);
            float2 w2 = cmul(w1, w1);
            float2 w3 = cmul(w2, w1);
            S[B]         = y0;
            S[B + q]     = cmul(y1, w1);
            S[B + 2 * q] = cmul(y2, w2);
            S[B + 3 * q] = cmul(y3, w3);
        }
        __syncthreads();
    }
    // final radix-2 on adjacent pairs (subproblem length 2), no twiddles
    #pragma unroll
    for (int it = 0; it < 8; ++it) {
        int p = tid + (it << 9);                // [0, 4096)
        int i0 = p << 1;
        float2 u = S[i0], v = S[i0 + 1];
        S[i0]     = make_float2(u.x + v.x, u.y + v.y);
        S[i0 + 1] = make_float2(u.x - v.x, u.y - v.y);
    }
    __syncthreads();
}

// ---------- inverse: radix-2 first, then 6x radix-4 DIT (L=8..8192) ----------
__device__ void inv_fft(float2* S, int tid) {
    #pragma unroll
    for (int it = 0; it < 8; ++it) {
        int p = tid + (it << 9);
        int i0 = p << 1;
        float2 u = S[i0], v = S[i0 + 1];
        S[i0]     = make_float2(u.x + v.x, u.y + v.y);
        S[i0 + 1] = make_float2(u.x - v.x, u.y - v.y);
    }
    __syncthreads();
    for (int lL = 3; lL <= 13; lL += 2) {
        const int L = 1 << lL;
        const int q = L >> 2;
        const float ang = 6.28318530717958647692f / (float)L;
        #pragma unroll
        for (int it = 0; it < 4; ++it) {
            int p = tid + (it << 9);
            int m = p & (q - 1);
            int B = ((p >> (lL - 2)) << lL) + m;
            float s1, c1;
            __sincosf(ang * (float)m, &s1, &c1);
            float2 w1 = make_float2(c1, s1);
            float2 w2 = cmul(w1, w1);
            float2 w3 = cmul(w2, w1);
            float2 z0 = S[B];
            float2 z1 = cmul(S[B + q], w1);
            float2 z2 = cmul(S[B + 2 * q], w2);
            float2 z3 = cmul(S[B + 3 * q], w3);
            float2 b0 = make_float2(z0.x + z2.x, z0.y + z2.y);
            float2 b1 = make_float2(z1.x + z3.x, z1.y + z3.y);
            float2 b2 = make_float2(z0.x - z2.x, z0.y - z2.y);
            float2 b3 = make_float2(z1.x - z3.x, z1.y - z3.y);
            S[B]         = make_float2(b0.x + b1.x, b0.y + b1.y);       // a0
            S[B + q]     = make_float2(b2.x - b3.y, b2.y + b3.x);       // a1 = b2 + i*b3
            S[B + 2 * q] = make_float2(b0.x - b1.x, b0.y - b1.y);       // a2
            S[B + 3 * q] = make_float2(b2.x + b3.y, b2.y - b3.x);       // a3 = b2 - i*b3
        }
        __syncthreads();
    }
}

__global__ __launch_bounds__(NTHR, 4) void fftconv_kernel(
    const float* __restrict__ Xp, const float* __restrict__ Tp,
    float* __restrict__ Op, int fast)
{
    __shared__ float2 S[NFFT];                  // 64 KB
    const int tid = threadIdx.x;
    const int bid = blockIdx.x;                 // [0, 2048)
    const int d = bid & 511;
    const int b = bid >> 9;

    const float* xrow; const float* trow; float* orow;
    int xs, ts, os;
    if (fast) {
        xrow = Xp + ((size_t)(b * 512 + d)) * 4096; xs = 1;
        trow = Tp + (size_t)d * 8192;               ts = 1;
        orow = Op + ((size_t)(b * 512 + d)) * 4096; os = 1;
    } else {
        xrow = Xp + (size_t)b * 4096 * 512 + d;     xs = 512;
        trow = Tp + d;                               ts = 512;
        orow = Op + (size_t)b * 4096 * 512 + d;     os = 512;
    }

    // ---- FFT of t row, keep spectrum in registers ----
    #pragma unroll
    for (int j = 0; j < 16; ++j) {
        int s = tid + (j << 9);
        S[s] = make_float2(trow[(size_t)s * ts], 0.f);
    }
    __syncthreads();
    fwd_fft(S, tid);

    float2 Treg[16];
    const float inv = 1.0f / (float)NFFT;
    #pragma unroll
    for (int j = 0; j < 16; ++j) {
        float2 v = S[tid + (j << 9)];
        Treg[j] = make_float2(v.x * inv, v.y * inv);  // fold 1/N into T spectrum
    }
    __syncthreads();

    // ---- FFT of zero-padded x row ----
    #pragma unroll
    for (int j = 0; j < 16; ++j) {
        int s = tid + (j << 9);
        S[s] = (j < 8) ? make_float2(xrow[(size_t)s * xs], 0.f)
                       : make_float2(0.f, 0.f);
    }
    __syncthreads();
    fwd_fft(S, tid);

    // ---- pointwise spectral multiply (digit-reversed order matches) ----
    #pragma unroll
    for (int j = 0; j < 16; ++j) {
        int s = tid + (j << 9);
        S[s] = cmul(S[s], Treg[j]);
    }
    __syncthreads();

    // ---- inverse FFT, natural-order output ----
    inv_fft(S, tid);

    // ---- write real part of first 4096 samples ----
    #pragma unroll
    for (int j = 0; j < 8; ++j) {
        int s = tid + (j << 9);
        orow[(size_t)s * os] = S[s].x;
    }
}

// batched tile transpose: in (batch, R, C) -> out (batch, C, R)
__global__ void transpose_k(const float* __restrict__ in, float* __restrict__ out,
                            int R, int C)
{
    __shared__ float tile[32][33];
    const int bz = blockIdx.z;
    const float* ip = in + (size_t)bz * R * C;
    float* op = out + (size_t)bz * R * C;
    const int c0 = blockIdx.x << 5;
    const int r0 = blockIdx.y << 5;
    const int tx = threadIdx.x, ty = threadIdx.y;
    #pragma unroll
    for (int k = 0; k < 32; k += 8)
        tile[ty + k][tx] = ip[(size_t)(r0 + ty + k) * C + (c0 + tx)];
    __syncthreads();
    #pragma unroll
    for (int k = 0; k < 32; k += 8)
        op[(size_t)(c0 + ty + k) * R + (r0 + tx)] = tile[tx][ty + k];
}

extern "C" void kernel_launch(void* const* d_in, const int* in_sizes, int n_in,
                              void* d_out, int out_size, void* d_ws, size_t ws_size,
                              hipStream_t stream)
{
    const float* x = (const float*)d_in[0];   // (4, 4096, 512)
    const float* t = (const float*)d_in[1];   // (8192, 512)
    float* out = (float*)d_out;               // (4, 4096, 512)

    const size_t xT_elems = (size_t)4 * 512 * 4096;   // 8388608
    const size_t tT_elems = (size_t)512 * 8192;       // 4194304
    const size_t need = (xT_elems + tT_elems) * sizeof(float);  // 48 MB

    if (ws_size >= need) {
        float* xT = (float*)d_ws;
        float* tT = xT + xT_elems;
        // x (4,4096,512) -> xT (4,512,4096)
        transpose_k<<<dim3(16, 128, 4), dim3(32, 8), 0, stream>>>(x, xT, 4096, 512);
        // t (8192,512) -> tT (512,8192)
        transpose_k<<<dim3(16, 256, 1), dim3(32, 8), 0, stream>>>(t, tT, 8192, 512);
        // conv per (b,d); output overwrites xT rows in-place
        fftconv_kernel<<<2048, NTHR, 0, stream>>>(xT, tT, xT, 1);
        // xT (4,512,4096) -> out (4,4096,512)
        transpose_k<<<dim3(128, 16, 4), dim3(32, 8), 0, stream>>>(xT, out, 512, 4096);
    } else {
        // fallback: strided (uncoalesced) direct access, still correct
        fftconv_kernel<<<2048, NTHR, 0, stream>>>(x, t, out, 0);
    }
}

// Round 2
// 153.739 us; speedup vs baseline: 1.2724x; 1.2724x over previous
//
#include <hip/hip_runtime.h>
#include <math.h>

// FFT circular conv, round 2: real-pair packing, no transposes.
//   For channel pair (2c, 2c+1): z[s] = x[b][s][2c] + i*x[b][s][2c+1]  (contiguous float2!)
//   ZX = FFT(pad(z)), ZT = FFT(t packed the same way), both radix-4 DIF (digit-reversed order).
//   Spectral separation via conjugate symmetry (partner slot r' = perm(N - perm^{-1}(r))):
//     Q[k] = (Xd*Td + i*Xe*Te)/N ; IFFT(Q) = o_d + i*o_e  -> direct float2 store to out.
//   3 FFTs per 2 channels (was 6), zero transpose kernels.
// LDS: two padded 8192-float2 buffers (pad 1 per 16 slots) = 139264 B -> 1 block/CU, 16 waves.

#define NFFT 8192
#define NTHR 1024
#define PAD(i) ((i) + ((i) >> 4))
#define LDS_ELEMS (NFFT + (NFFT >> 4))   // 8704 float2 per buffer

__device__ __forceinline__ float2 cmul(float2 a, float2 b) {
    return make_float2(a.x * b.x - a.y * b.y, a.x * b.y + a.y * b.x);
}

// storage permutation of radix-4 DIF (L=8192..8) + final radix-2:
// slot s of freq k: s = (k1k0)<<11 | (k3k2)<<9 | ... | (k11k10)<<1 | k12
__device__ __forceinline__ int perm_fwd(int k) {   // freq -> slot
    unsigned y = __brev((unsigned)k) >> 19;        // 13-bit bit-reversal
    unsigned z = y >> 1;
    unsigned w = ((z & 0x555u) << 1) | ((z >> 1) & 0x555u);  // swap adjacent pairs
    return (int)((w << 1) | (y & 1u));
}
__device__ __forceinline__ int perm_inv(int s) {   // slot -> freq
    unsigned u = (unsigned)s >> 1;
    unsigned r12 = __brev(u) >> 20;                // 12-bit bit-reversal
    unsigned low = ((r12 & 0x555u) << 1) | ((r12 >> 1) & 0x555u);
    return (int)((((unsigned)s & 1u) << 12) | low);
}

__device__ __forceinline__ void bfly4_fwd(float2* S, int iB, int i1, int i2, int i3,
                                          float2 w1, float2 w2, float2 w3) {
    float2 a0 = S[iB], a1 = S[i1], a2 = S[i2], a3 = S[i3];
    float2 b0 = make_float2(a0.x + a2.x, a0.y + a2.y);
    float2 b1 = make_float2(a1.x + a3.x, a1.y + a3.y);
    float2 b2 = make_float2(a0.x - a2.x, a0.y - a2.y);
    float2 b3 = make_float2(a1.x - a3.x, a1.y - a3.y);
    float2 y0 = make_float2(b0.x + b1.x, b0.y + b1.y);
    float2 y2 = make_float2(b0.x - b1.x, b0.y - b1.y);
    float2 y1 = make_float2(b2.x + b3.y, b2.y - b3.x);  // b2 - i*b3
    float2 y3 = make_float2(b2.x - b3.y, b2.y + b3.x);  // b2 + i*b3
    S[iB] = y0;
    S[i1] = cmul(y1, w1);
    S[i2] = cmul(y2, w2);
    S[i3] = cmul(y3, w3);
}

__global__ __launch_bounds__(NTHR, 1) void fftconv2(
    const float* __restrict__ X, const float* __restrict__ T,
    float* __restrict__ O)
{
    extern __shared__ float2 LDS[];
    float2* SX = LDS;
    float2* ST = LDS + LDS_ELEMS;

    const int tid = threadIdx.x;

    // XCD-aware swizzle: the 8 logical blocks sharing each 64B channel line
    // (consecutive c, same b) land on the same XCD (assumes xcd = hw_bid % 8).
    {
    }
    int h = blockIdx.x;
    int Xc = h & 7, sl = h >> 3;
    int lbid = ((sl >> 3) << 6) | (Xc << 3) | (sl & 7);   // bijective on [0,1024)
    const int b = lbid >> 8;
    const int c = lbid & 255;
    const int dbase = c << 1;

    // ---- load t (packed pair) and zero-padded x (packed pair) ----
    #pragma unroll
    for (int it = 0; it < 8; ++it) {
        int j = tid + (it << 10);
        ST[PAD(j)] = *(const float2*)(T + (size_t)j * 512 + dbase);
        SX[PAD(j)] = (j < 4096)
            ? *(const float2*)(X + ((size_t)b * 4096 + j) * 512 + dbase)
            : make_float2(0.f, 0.f);
    }
    __syncthreads();

    // ---- forward FFT on BOTH buffers, shared twiddles ----
    for (int lL = 13; lL >= 3; lL -= 2) {
        const int q = 1 << (lL - 2);
        const float ang = -6.28318530717958647692f / (float)(1 << lL);
        #pragma unroll
        for (int it = 0; it < 2; ++it) {
            int p = tid + (it << 10);
            int m = p & (q - 1);
            int B = ((p >> (lL - 2)) << lL) + m;
            float s1, c1;
            __sincosf(ang * (float)m, &s1, &c1);
            float2 w1 = make_float2(c1, s1);
            float2 w2 = cmul(w1, w1);
            float2 w3 = cmul(w2, w1);
            int iB = PAD(B), i1 = PAD(B + q), i2 = PAD(B + 2 * q), i3 = PAD(B + 3 * q);
            bfly4_fwd(SX, iB, i1, i2, i3, w1, w2, w3);
            bfly4_fwd(ST, iB, i1, i2, i3, w1, w2, w3);
        }
        __syncthreads();
    }
    #pragma unroll
    for (int it = 0; it < 4; ++it) {             // final radix-2, both buffers
        int p = tid + (it << 10);
        int i0 = PAD(p << 1);                    // pair stays adjacent under PAD
        {
            float2 u = SX[i0], v = SX[i0 + 1];
            SX[i0]     = make_float2(u.x + v.x, u.y + v.y);
            SX[i0 + 1] = make_float2(u.x - v.x, u.y - v.y);
        }
        {
            float2 u = ST[i0], v = ST[i0 + 1];
            ST[i0]     = make_float2(u.x + v.x, u.y + v.y);
            ST[i0 + 1] = make_float2(u.x - v.x, u.y - v.y);
        }
    }
    __syncthreads();

    // ---- conjugate-symmetry separation + spectral multiply ----
    // Pairs (r, r') are disjoint (involution), each handled by min-owner: no races.
    const float sc = 1.0f / (4.0f * (float)NFFT);
    #pragma unroll
    for (int it = 0; it < 8; ++it) {
        int r = tid + (it << 10);
        int k = perm_inv(r);
        int r2 = perm_fwd((NFFT - k) & (NFFT - 1));
        if (r > r2) continue;
        float2 a  = SX[PAD(r)],  A = SX[PAD(r2)];
        float2 cc = ST[PAD(r)],  C = ST[PAD(r2)];
        float2 P1 = make_float2(a.x + A.x,  a.y - A.y);   // a + conj(A)
        float2 P2 = make_float2(cc.x + C.x, cc.y - C.y);  // c + conj(C)
        float2 M1 = make_float2(a.x - A.x,  a.y + A.y);   // a - conj(A)
        float2 M2 = make_float2(cc.x - C.x, cc.y + C.y);  // c - conj(C)
        float2 U = cmul(P1, P2), W = cmul(M1, M2);
        // Q[r] = (U - i*W)/4N ; Q[r'] = conj-role swap = (conj(U) - i*conj(W))/4N
        SX[PAD(r)]  = make_float2((U.x + W.y) * sc,  (U.y - W.x) * sc);
        SX[PAD(r2)] = make_float2((U.x - W.y) * sc, -(U.y + W.x) * sc);
    }
    __syncthreads();

    // ---- inverse FFT on SX: radix-2 first, then radix-4 DIT -> natural order ----
    #pragma unroll
    for (int it = 0; it < 4; ++it) {
        int p = tid + (it << 10);
        int i0 = PAD(p << 1);
        float2 u = SX[i0], v = SX[i0 + 1];
        SX[i0]     = make_float2(u.x + v.x, u.y + v.y);
        SX[i0 + 1] = make_float2(u.x - v.x, u.y - v.y);
    }
    __syncthreads();
    for (int lL = 3; lL <= 13; lL += 2) {
        const int q = 1 << (lL - 2);
        const float ang = 6.28318530717958647692f / (float)(1 << lL);
        #pragma unroll
        for (int it = 0; it < 2; ++it) {
            int p = tid + (it << 10);
            int m = p & (q - 1);
            int B = ((p >> (lL - 2)) << lL) + m;
            float s1, c1;
            __sincosf(ang * (float)m, &s1, &c1);
            float2 w1 = make_float2(c1, s1);
            float2 w2 = cmul(w1, w1);
            float2 w3 = cmul(w2, w1);
            int iB = PAD(B), i1 = PAD(B + q), i2 = PAD(B + 2 * q), i3 = PAD(B + 3 * q);
            float2 z0 = SX[iB];
            float2 z1 = cmul(SX[i1], w1);
            float2 z2 = cmul(SX[i2], w2);
            float2 z3 = cmul(SX[i3], w3);
            float2 b0 = make_float2(z0.x + z2.x, z0.y + z2.y);
            float2 b1 = make_float2(z1.x + z3.x, z1.y + z3.y);
            float2 b2 = make_float2(z0.x - z2.x, z0.y - z2.y);
            float2 b3 = make_float2(z1.x - z3.x, z1.y - z3.y);
            SX[iB] = make_float2(b0.x + b1.x, b0.y + b1.y);
            SX[i1] = make_float2(b2.x - b3.y, b2.y + b3.x);  // b2 + i*b3
            SX[i2] = make_float2(b0.x - b1.x, b0.y - b1.y);
            SX[i3] = make_float2(b2.x + b3.y, b2.y - b3.x);  // b2 - i*b3
        }
        __syncthreads();
    }

    // ---- store: Re -> channel 2c, Im -> channel 2c+1, directly in (b,n,d) ----
    #pragma unroll
    for (int it = 0; it < 4; ++it) {
        int s = tid + (it << 10);
        *(float2*)(O + ((size_t)b * 4096 + s) * 512 + dbase) = SX[PAD(s)];
    }
}

extern "C" void kernel_launch(void* const* d_in, const int* in_sizes, int n_in,
                              void* d_out, int out_size, void* d_ws, size_t ws_size,
                              hipStream_t stream)
{
    const float* x = (const float*)d_in[0];   // (4, 4096, 512)
    const float* t = (const float*)d_in[1];   // (8192, 512)
    float* out = (float*)d_out;               // (4, 4096, 512)

    const int lds_bytes = (int)(2 * LDS_ELEMS * sizeof(float2));  // 139264
    (void)hipFuncSetAttribute((const void*)fftconv2,
                              hipFuncAttributeMaxDynamicSharedMemorySize, lds_bytes);

    fftconv2<<<1024, NTHR, lds_bytes, stream>>>(x, t, out);
}

// Round 3
// 118.211 us; speedup vs baseline: 1.6548x; 1.3005x over previous
//
#include <hip/hip_runtime.h>
#include <math.h>

// Round 3: T-spectrum precompute + single-buffer conv kernel (2 blocks/CU).
//   K_T  (256 blocks): ZT = FFT(t[:,2c] + i t[:,2c+1]); separate to (Td,Te)/N,
//                      store float4 per slot -> ws (32 MB), coalesced.
//   K_X (1024 blocks): ZX = FFT(pad(x pair)) in one LDS buffer (69.6 KB);
//                      Q[r] = Xd*Td + i*Xe*Te (Tsep read coalesced, X partner in LDS,
//                      q held in regs across one barrier); inverse FFT; last stage
//                      fused with the global store (upper half discarded).
// FFT: radix-4 DIF fwd (digit-reversed slots) / radix-4 DIT inv, PAD(i)=i+(i>>4).

#define NFFT 8192
#define NTHR 1024
#define PAD(i) ((i) + ((i) >> 4))
#define LDS_ELEMS (NFFT + (NFFT >> 4))          // 8704 float2 = 69632 B
#define TWO_PI 6.28318530717958647692f

__device__ __forceinline__ float2 cmul(float2 a, float2 b) {
    return make_float2(a.x * b.x - a.y * b.y, a.x * b.y + a.y * b.x);
}

// slot s of freq k for radix-4 DIF (L=8192..8) + final radix-2
__device__ __forceinline__ int perm_fwd(int k) {   // freq -> slot
    unsigned y = __brev((unsigned)k) >> 19;
    unsigned z = y >> 1;
    unsigned w = ((z & 0x555u) << 1) | ((z >> 1) & 0x555u);
    return (int)((w << 1) | (y & 1u));
}
__device__ __forceinline__ int perm_inv(int s) {   // slot -> freq
    unsigned u = (unsigned)s >> 1;
    unsigned r12 = __brev(u) >> 20;
    unsigned low = ((r12 & 0x555u) << 1) | ((r12 >> 1) & 0x555u);
    return (int)((((unsigned)s & 1u) << 12) | low);
}

__device__ __forceinline__ void r4_dif_stage(float2* S, int tid, int lL) {
    const int q = 1 << (lL - 2);
    const float ang = -TWO_PI / (float)(1 << lL);
    #pragma unroll
    for (int it = 0; it < 2; ++it) {
        int p = tid + (it << 10);
        int m = p & (q - 1);
        int B = ((p >> (lL - 2)) << lL) + m;
        float s1, c1;
        __sincosf(ang * (float)m, &s1, &c1);
        float2 w1 = make_float2(c1, s1);
        float2 w2 = cmul(w1, w1);
        float2 w3 = cmul(w2, w1);
        int iB = PAD(B), i1 = PAD(B + q), i2 = PAD(B + 2 * q), i3 = PAD(B + 3 * q);
        float2 a0 = S[iB], a1 = S[i1], a2 = S[i2], a3 = S[i3];
        float2 b0 = make_float2(a0.x + a2.x, a0.y + a2.y);
        float2 b1 = make_float2(a1.x + a3.x, a1.y + a3.y);
        float2 b2 = make_float2(a0.x - a2.x, a0.y - a2.y);
        float2 b3 = make_float2(a1.x - a3.x, a1.y - a3.y);
        S[iB] = make_float2(b0.x + b1.x, b0.y + b1.y);
        S[i1] = cmul(make_float2(b2.x + b3.y, b2.y - b3.x), w1);   // b2 - i*b3
        S[i2] = cmul(make_float2(b0.x - b1.x, b0.y - b1.y), w2);
        S[i3] = cmul(make_float2(b2.x - b3.y, b2.y + b3.x), w3);   // b2 + i*b3
    }
    __syncthreads();
}

// adjacent-pair radix-2 (fwd-final and inv-first are the same op)
__device__ __forceinline__ void r2_pairs(float2* S, int tid) {
    #pragma unroll
    for (int it = 0; it < 4; ++it) {
        int i0 = PAD((tid + (it << 10)) << 1);   // pair stays adjacent under PAD
        float2 u = S[i0], v = S[i0 + 1];
        S[i0]     = make_float2(u.x + v.x, u.y + v.y);
        S[i0 + 1] = make_float2(u.x - v.x, u.y - v.y);
    }
    __syncthreads();
}

__device__ __forceinline__ void inv_r4_stage(float2* S, int tid, int lL) {
    const int q = 1 << (lL - 2);
    const float ang = TWO_PI / (float)(1 << lL);
    #pragma unroll
    for (int it = 0; it < 2; ++it) {
        int p = tid + (it << 10);
        int m = p & (q - 1);
        int B = ((p >> (lL - 2)) << lL) + m;
        float s1, c1;
        __sincosf(ang * (float)m, &s1, &c1);
        float2 w1 = make_float2(c1, s1);
        float2 w2 = cmul(w1, w1);
        float2 w3 = cmul(w2, w1);
        int iB = PAD(B), i1 = PAD(B + q), i2 = PAD(B + 2 * q), i3 = PAD(B + 3 * q);
        float2 z0 = S[iB];
        float2 z1 = cmul(S[i1], w1);
        float2 z2 = cmul(S[i2], w2);
        float2 z3 = cmul(S[i3], w3);
        float2 b0 = make_float2(z0.x + z2.x, z0.y + z2.y);
        float2 b1 = make_float2(z1.x + z3.x, z1.y + z3.y);
        float2 b2 = make_float2(z0.x - z2.x, z0.y - z2.y);
        float2 b3 = make_float2(z1.x - z3.x, z1.y - z3.y);
        S[iB] = make_float2(b0.x + b1.x, b0.y + b1.y);
        S[i1] = make_float2(b2.x - b3.y, b2.y + b3.x);   // b2 + i*b3
        S[i2] = make_float2(b0.x - b1.x, b0.y - b1.y);
        S[i3] = make_float2(b2.x + b3.y, b2.y - b3.x);   // b2 - i*b3
    }
    __syncthreads();
}

// ---------------- T-spectrum precompute: 256 blocks, one per channel pair ----
__global__ __launch_bounds__(NTHR, 4) void tsep_kernel(
    const float* __restrict__ T, float4* __restrict__ Tsep)
{
    extern __shared__ float2 ST[];
    const int tid = threadIdx.x;
    const int c = blockIdx.x;              // [0,256)
    const int dbase = c << 1;

    #pragma unroll
    for (int it = 0; it < 8; ++it) {
        int j = tid + (it << 10);
        ST[PAD(j)] = *(const float2*)(T + (size_t)j * 512 + dbase);
    }
    __syncthreads();
    for (int lL = 13; lL >= 3; lL -= 2) r4_dif_stage(ST, tid, lL);
    r2_pairs(ST, tid);

    const float sc = 0.5f / (float)NFFT;
    float4* tb = Tsep + (size_t)c * NFFT;
    #pragma unroll
    for (int it = 0; it < 8; ++it) {
        int r = tid + (it << 10);
        int k = perm_inv(r);
        int r2 = perm_fwd((NFFT - k) & (NFFT - 1));
        float2 Zk = ST[PAD(r)], Zn = ST[PAD(r2)];
        // Td = (Zk + conj(Zn))*sc ; Te = -i*(Zk - conj(Zn))*sc
        tb[r] = make_float4((Zk.x + Zn.x) * sc, (Zk.y - Zn.y) * sc,
                            (Zk.y + Zn.y) * sc, (Zn.x - Zk.x) * sc);
    }
}

// ---------------- main conv: 1024 blocks, 2 per CU --------------------------
__global__ __launch_bounds__(NTHR, 8) void fftconv3(
    const float* __restrict__ X, const float4* __restrict__ Tsep,
    float* __restrict__ O)
{
    extern __shared__ float2 SX[];
    const int tid = threadIdx.x;

    // XCD swizzle: 8 consecutive-c blocks (sharing 64B lines) per XCD;
    // same c across b stays on one XCD for Tsep L2 reuse.
    int h = blockIdx.x;
    int Xc = h & 7, sl = h >> 3;
    int lbid = ((sl >> 3) << 6) | (Xc << 3) | (sl & 7);
    const int b = lbid >> 8;
    const int c = lbid & 255;
    const int dbase = c << 1;

    // ---- load lower half only (upper half is zero-pad, never touched) ----
    #pragma unroll
    for (int it = 0; it < 4; ++it) {
        int j = tid + (it << 10);
        SX[PAD(j)] = *(const float2*)(X + ((size_t)b * 4096 + j) * 512 + dbase);
    }
    __syncthreads();

    // ---- forward FFT, first stage specialized for zero upper half ----
    {
        const float ang = -TWO_PI / (float)NFFT;
        #pragma unroll
        for (int it = 0; it < 2; ++it) {
            int m = tid + (it << 10);          // [0,2048)
            float2 a0 = SX[PAD(m)], a1 = SX[PAD(m + 2048)];
            float s1, c1;
            __sincosf(ang * (float)m, &s1, &c1);
            float2 w1 = make_float2(c1, s1);
            float2 w2 = cmul(w1, w1);
            float2 w3 = cmul(w2, w1);
            SX[PAD(m)]        = make_float2(a0.x + a1.x, a0.y + a1.y);
            SX[PAD(m + 2048)] = cmul(make_float2(a0.x + a1.y, a0.y - a1.x), w1); // a0-i*a1
            SX[PAD(m + 4096)] = cmul(make_float2(a0.x - a1.x, a0.y - a1.y), w2);
            SX[PAD(m + 6144)] = cmul(make_float2(a0.x - a1.y, a0.y + a1.x), w3); // a0+i*a1
        }
        __syncthreads();
    }
    for (int lL = 11; lL >= 3; lL -= 2) r4_dif_stage(SX, tid, lL);
    r2_pairs(SX, tid);

    // ---- separation + spectral multiply (q in regs across one barrier) ----
    const float4* tb = Tsep + (size_t)c * NFFT;
    float2 qreg[8];
    #pragma unroll
    for (int it = 0; it < 8; ++it) {
        int r = tid + (it << 10);
        int k = perm_inv(r);
        int r2 = perm_fwd((NFFT - k) & (NFFT - 1));
        float2 Zk = SX[PAD(r)], Zn = SX[PAD(r2)];
        float4 tv = tb[r];
        float2 Xd = make_float2((Zk.x + Zn.x) * 0.5f, (Zk.y - Zn.y) * 0.5f);
        float2 Xe = make_float2((Zk.y + Zn.y) * 0.5f, (Zn.x - Zk.x) * 0.5f);
        float2 A  = cmul(Xd, make_float2(tv.x, tv.y));
        float2 Bv = cmul(Xe, make_float2(tv.z, tv.w));
        qreg[it] = make_float2(A.x - Bv.y, A.y + Bv.x);   // A + i*Bv
    }
    __syncthreads();
    #pragma unroll
    for (int it = 0; it < 8; ++it)
        SX[PAD(tid + (it << 10))] = qreg[it];
    __syncthreads();

    // ---- inverse FFT; final stage fused with store, upper half discarded ----
    r2_pairs(SX, tid);
    for (int lL = 3; lL <= 11; lL += 2) inv_r4_stage(SX, tid, lL);
    {
        const float ang = TWO_PI / (float)NFFT;
        #pragma unroll
        for (int it = 0; it < 2; ++it) {
            int m = tid + (it << 10);          // [0,2048)
            float s1, c1;
            __sincosf(ang * (float)m, &s1, &c1);
            float2 w1 = make_float2(c1, s1);
            float2 w2 = cmul(w1, w1);
            float2 w3 = cmul(w2, w1);
            float2 z0 = SX[PAD(m)];
            float2 z1 = cmul(SX[PAD(m + 2048)], w1);
            float2 z2 = cmul(SX[PAD(m + 4096)], w2);
            float2 z3 = cmul(SX[PAD(m + 6144)], w3);
            float2 b0 = make_float2(z0.x + z2.x, z0.y + z2.y);
            float2 b1 = make_float2(z1.x + z3.x, z1.y + z3.y);
            float2 b2 = make_float2(z0.x - z2.x, z0.y - z2.y);
            float2 b3 = make_float2(z1.x - z3.x, z1.y - z3.y);
            // time index m: Re->ch 2c, Im->ch 2c+1 ; time index m+2048 likewise
            *(float2*)(O + ((size_t)b * 4096 + m) * 512 + dbase) =
                make_float2(b0.x + b1.x, b0.y + b1.y);
            *(float2*)(O + ((size_t)b * 4096 + m + 2048) * 512 + dbase) =
                make_float2(b2.x - b3.y, b2.y + b3.x);        // b2 + i*b3
        }
    }
}

// ---------------- fallback (ws too small): round-2 two-buffer kernel --------
__global__ __launch_bounds__(NTHR, 1) void fftconv2(
    const float* __restrict__ X, const float* __restrict__ T,
    float* __restrict__ O)
{
    extern __shared__ float2 LDS[];
    float2* SX = LDS;
    float2* ST = LDS + LDS_ELEMS;
    const int tid = threadIdx.x;
    int h = blockIdx.x;
    int Xc = h & 7, sl = h >> 3;
    int lbid = ((sl >> 3) << 6) | (Xc << 3) | (sl & 7);
    const int b = lbid >> 8;
    const int c = lbid & 255;
    const int dbase = c << 1;

    #pragma unroll
    for (int it = 0; it < 8; ++it) {
        int j = tid + (it << 10);
        ST[PAD(j)] = *(const float2*)(T + (size_t)j * 512 + dbase);
        SX[PAD(j)] = (j < 4096)
            ? *(const float2*)(X + ((size_t)b * 4096 + j) * 512 + dbase)
            : make_float2(0.f, 0.f);
    }
    __syncthreads();
    for (int lL = 13; lL >= 3; lL -= 2) {
        const int q = 1 << (lL - 2);
        const float ang = -TWO_PI / (float)(1 << lL);
        #pragma unroll
        for (int it = 0; it < 2; ++it) {
            int p = tid + (it << 10);
            int m = p & (q - 1);
            int B = ((p >> (lL - 2)) << lL) + m;
            float s1, c1;
            __sincosf(ang * (float)m, &s1, &c1);
            float2 w1 = make_float2(c1, s1);
            float2 w2 = cmul(w1, w1);
            float2 w3 = cmul(w2, w1);
            int iB = PAD(B), i1 = PAD(B + q), i2 = PAD(B + 2 * q), i3 = PAD(B + 3 * q);
            #pragma unroll
            for (int bi = 0; bi < 2; ++bi) {
                float2* S = bi ? ST : SX;
                float2 a0 = S[iB], a1 = S[i1], a2 = S[i2], a3 = S[i3];
                float2 b0 = make_float2(a0.x + a2.x, a0.y + a2.y);
                float2 b1 = make_float2(a1.x + a3.x, a1.y + a3.y);
                float2 b2 = make_float2(a0.x - a2.x, a0.y - a2.y);
                float2 b3 = make_float2(a1.x - a3.x, a1.y - a3.y);
                S[iB] = make_float2(b0.x + b1.x, b0.y + b1.y);
                S[i1] = cmul(make_float2(b2.x + b3.y, b2.y - b3.x), w1);
                S[i2] = cmul(make_float2(b0.x - b1.x, b0.y - b1.y), w2);
                S[i3] = cmul(make_float2(b2.x - b3.y, b2.y + b3.x), w3);
            }
        }
        __syncthreads();
    }
    #pragma unroll
    for (int it = 0; it < 4; ++it) {
        int i0 = PAD((tid + (it << 10)) << 1);
        #pragma unroll
        for (int bi = 0; bi < 2; ++bi) {
            float2* S = bi ? ST : SX;
            float2 u = S[i0], v = S[i0 + 1];
            S[i0]     = make_float2(u.x + v.x, u.y + v.y);
            S[i0 + 1] = make_float2(u.x - v.x, u.y - v.y);
        }
    }
    __syncthreads();
    const float sc = 1.0f / (4.0f * (float)NFFT);
    #pragma unroll
    for (int it = 0; it < 8; ++it) {
        int r = tid + (it << 10);
        int k = perm_inv(r);
        int r2 = perm_fwd((NFFT - k) & (NFFT - 1));
        if (r > r2) continue;
        float2 a  = SX[PAD(r)],  A = SX[PAD(r2)];
        float2 cc = ST[PAD(r)],  C = ST[PAD(r2)];
        float2 P1 = make_float2(a.x + A.x,  a.y - A.y);
        float2 P2 = make_float2(cc.x + C.x, cc.y - C.y);
        float2 M1 = make_float2(a.x - A.x,  a.y + A.y);
        float2 M2 = make_float2(cc.x - C.x, cc.y + C.y);
        float2 U = cmul(P1, P2), W = cmul(M1, M2);
        SX[PAD(r)]  = make_float2((U.x + W.y) * sc,  (U.y - W.x) * sc);
        SX[PAD(r2)] = make_float2((U.x - W.y) * sc, -(U.y + W.x) * sc);
    }
    __syncthreads();
    #pragma unroll
    for (int it = 0; it < 4; ++it) {
        int i0 = PAD((tid + (it << 10)) << 1);
        float2 u = SX[i0], v = SX[i0 + 1];
        SX[i0]     = make_float2(u.x + v.x, u.y + v.y);
        SX[i0 + 1] = make_float2(u.x - v.x, u.y - v.y);
    }
    __syncthreads();
    for (int lL = 3; lL <= 13; lL += 2) inv_r4_stage(SX, tid, lL);
    #pragma unroll
    for (int it = 0; it < 4; ++it) {
        int s = tid + (it << 10);
        *(float2*)(O + ((size_t)b * 4096 + s) * 512 + dbase) = SX[PAD(s)];
    }
}

extern "C" void kernel_launch(void* const* d_in, const int* in_sizes, int n_in,
                              void* d_out, int out_size, void* d_ws, size_t ws_size,
                              hipStream_t stream)
{
    const float* x = (const float*)d_in[0];   // (4, 4096, 512)
    const float* t = (const float*)d_in[1];   // (8192, 512)
    float* out = (float*)d_out;               // (4, 4096, 512)

    const size_t tsep_bytes = (size_t)256 * NFFT * sizeof(float4);   // 32 MB
    const int lds1 = (int)(LDS_ELEMS * sizeof(float2));              // 69632

    if (ws_size >= tsep_bytes) {
        float4* tsep = (float4*)d_ws;
        (void)hipFuncSetAttribute((const void*)tsep_kernel,
                                  hipFuncAttributeMaxDynamicSharedMemorySize, lds1);
        (void)hipFuncSetAttribute((const void*)fftconv3,
                                  hipFuncAttributeMaxDynamicSharedMemorySize, lds1);
        tsep_kernel<<<256, NTHR, lds1, stream>>>(t, tsep);
        fftconv3<<<1024, NTHR, lds1, stream>>>(x, tsep, out);
    } else {
        const int lds2 = 2 * lds1;
        (void)hipFuncSetAttribute((const void*)fftconv2,
                                  hipFuncAttributeMaxDynamicSharedMemorySize, lds2);
        fftconv2<<<1024, NTHR, lds2, stream>>>(x, t, out);
    }
}

// Round 4
// 117.843 us; speedup vs baseline: 1.6600x; 1.0031x over previous
//
#include <hip/hip_runtime.h>
#include <math.h>

// Round 4: register radix-8 FFT (8192 = 8*8*8*8*2), 1024 threads = 1 butterfly/thread/stage.
//   fwd: load->regs stage1 (4 zero inputs => two DFT4s), 3 LDS r8 stages.
//   fused pass: fwd-r2 + conj-symmetry separation + Tsep mul + inv-r2, all in regs (1 barrier).
//   inv: 3 LDS r8 stages, final stage fused with store (only 4 of 8 outputs kept).
// Slot permutation: s = octal-digit-reversal of k's low 12 bits, LSB = k's bit 12.
// Partner of slot pair (2u,2u+1) is (2v+1,2v), v = rev8(4096-rev8(u)); u=0 self-paired.

#define NFFT 8192
#define NTHR 1024
#define PAD(i) ((i) + ((i) >> 4))
#define LDS_ELEMS (NFFT + (NFFT >> 4))          // 8704 float2 = 69632 B
#define TWO_PI 6.28318530717958647692f
#define RSQRT2 0.70710678118654752440f

__device__ __forceinline__ float2 cadd(float2 a, float2 b){ return make_float2(a.x+b.x, a.y+b.y); }
__device__ __forceinline__ float2 csub(float2 a, float2 b){ return make_float2(a.x-b.x, a.y-b.y); }
__device__ __forceinline__ float2 cmul(float2 a, float2 b){ return make_float2(a.x*b.x - a.y*b.y, a.x*b.y + a.y*b.x); }
__device__ __forceinline__ float2 mulnegi(float2 a){ return make_float2(a.y, -a.x); }   // * (-i)
__device__ __forceinline__ float2 mulposi(float2 a){ return make_float2(-a.y, a.x); }   // * (+i)
__device__ __forceinline__ float2 mulw81(float2 z){ return make_float2(RSQRT2*(z.x+z.y), RSQRT2*(z.y-z.x)); }  // * e^{-i pi/4}
__device__ __forceinline__ float2 mulw83(float2 z){ return make_float2(RSQRT2*(z.y-z.x), -RSQRT2*(z.x+z.y)); } // * e^{-i 3pi/4}
__device__ __forceinline__ float2 mulv81(float2 z){ return make_float2(RSQRT2*(z.x-z.y), RSQRT2*(z.x+z.y)); }  // * e^{+i pi/4}
__device__ __forceinline__ float2 mulv83(float2 z){ return make_float2(-RSQRT2*(z.x+z.y), RSQRT2*(z.x-z.y)); } // * e^{+i 3pi/4}

__device__ __forceinline__ int rev8_12(int u) {   // 4-octal-digit reversal, involution
    return ((u & 7) << 9) | (((u >> 3) & 7) << 6) | (((u >> 6) & 7) << 3) | ((u >> 9) & 7);
}

__device__ __forceinline__ void dft8_fwd(float2& a0, float2& a1, float2& a2, float2& a3,
                                         float2& a4, float2& a5, float2& a6, float2& a7) {
    float2 s02 = cadd(a0,a4), d02 = csub(a0,a4), s13 = cadd(a2,a6), d13 = csub(a2,a6);
    float2 E0 = cadd(s02,s13), E2 = csub(s02,s13);
    float2 E1 = cadd(d02, mulnegi(d13)), E3 = csub(d02, mulnegi(d13));
    float2 t02 = cadd(a1,a5), u02 = csub(a1,a5), t13 = cadd(a3,a7), u13 = csub(a3,a7);
    float2 O0 = cadd(t02,t13), O2 = csub(t02,t13);
    float2 O1 = cadd(u02, mulnegi(u13)), O3 = csub(u02, mulnegi(u13));
    float2 W1 = mulw81(O1), W2 = mulnegi(O2), W3 = mulw83(O3);
    a0 = cadd(E0,O0); a4 = csub(E0,O0);
    a1 = cadd(E1,W1); a5 = csub(E1,W1);
    a2 = cadd(E2,W2); a6 = csub(E2,W2);
    a3 = cadd(E3,W3); a7 = csub(E3,W3);
}

__device__ __forceinline__ void dft8_inv(float2& a0, float2& a1, float2& a2, float2& a3,
                                         float2& a4, float2& a5, float2& a6, float2& a7) {
    float2 s02 = cadd(a0,a4), d02 = csub(a0,a4), s13 = cadd(a2,a6), d13 = csub(a2,a6);
    float2 P0 = cadd(s02,s13), P2 = csub(s02,s13);
    float2 P1 = cadd(d02, mulposi(d13)), P3 = csub(d02, mulposi(d13));
    float2 t02 = cadd(a1,a5), u02 = csub(a1,a5), t13 = cadd(a3,a7), u13 = csub(a3,a7);
    float2 Q0 = cadd(t02,t13), Q2 = csub(t02,t13);
    float2 Q1 = cadd(u02, mulposi(u13)), Q3 = csub(u02, mulposi(u13));
    float2 W1 = mulv81(Q1), W2 = mulposi(Q2), W3 = mulv83(Q3);
    a0 = cadd(P0,Q0); a4 = csub(P0,Q0);
    a1 = cadd(P1,W1); a5 = csub(P1,W1);
    a2 = cadd(P2,W2); a6 = csub(P2,W2);
    a3 = cadd(P3,W3); a7 = csub(P3,W3);
}

template<int LQ>
__device__ __forceinline__ void fwd_stage(float2* S, int tid) {
    const int q = 1 << LQ;
    const int m = tid & (q - 1);
    const int B = ((tid >> LQ) << (LQ + 3)) + m;
    float2 a0 = S[PAD(B)],       a1 = S[PAD(B + q)],   a2 = S[PAD(B + 2*q)], a3 = S[PAD(B + 3*q)];
    float2 a4 = S[PAD(B + 4*q)], a5 = S[PAD(B + 5*q)], a6 = S[PAD(B + 6*q)], a7 = S[PAD(B + 7*q)];
    dft8_fwd(a0,a1,a2,a3,a4,a5,a6,a7);
    float sn, cs;
    __sincosf(-TWO_PI * (float)m / (float)(q << 3), &sn, &cs);
    float2 w1 = make_float2(cs, sn);
    S[PAD(B)] = a0;
    float2 w = w1;
    S[PAD(B +   q)] = cmul(a1, w); w = cmul(w, w1);
    S[PAD(B + 2*q)] = cmul(a2, w); w = cmul(w, w1);
    S[PAD(B + 3*q)] = cmul(a3, w); w = cmul(w, w1);
    S[PAD(B + 4*q)] = cmul(a4, w); w = cmul(w, w1);
    S[PAD(B + 5*q)] = cmul(a5, w); w = cmul(w, w1);
    S[PAD(B + 6*q)] = cmul(a6, w); w = cmul(w, w1);
    S[PAD(B + 7*q)] = cmul(a7, w);
}

template<int LQ>
__device__ __forceinline__ void inv_stage(float2* S, int tid) {
    const int q = 1 << LQ;
    const int m = tid & (q - 1);
    const int B = ((tid >> LQ) << (LQ + 3)) + m;
    float sn, cs;
    __sincosf(TWO_PI * (float)m / (float)(q << 3), &sn, &cs);
    float2 w1 = make_float2(cs, sn);
    float2 a0 = S[PAD(B)];
    float2 w = w1;
    float2 a1 = cmul(S[PAD(B +   q)], w); w = cmul(w, w1);
    float2 a2 = cmul(S[PAD(B + 2*q)], w); w = cmul(w, w1);
    float2 a3 = cmul(S[PAD(B + 3*q)], w); w = cmul(w, w1);
    float2 a4 = cmul(S[PAD(B + 4*q)], w); w = cmul(w, w1);
    float2 a5 = cmul(S[PAD(B + 5*q)], w); w = cmul(w, w1);
    float2 a6 = cmul(S[PAD(B + 6*q)], w); w = cmul(w, w1);
    float2 a7 = cmul(S[PAD(B + 7*q)], w);
    dft8_inv(a0,a1,a2,a3,a4,a5,a6,a7);
    S[PAD(B)]       = a0; S[PAD(B +   q)] = a1; S[PAD(B + 2*q)] = a2; S[PAD(B + 3*q)] = a3;
    S[PAD(B + 4*q)] = a4; S[PAD(B + 5*q)] = a5; S[PAD(B + 6*q)] = a6; S[PAD(B + 7*q)] = a7;
}

// ---------------- T-spectrum precompute: 256 blocks ----------------
__global__ __launch_bounds__(NTHR, 8) void tsep_k(
    const float* __restrict__ T, float4* __restrict__ Tsep)
{
    extern __shared__ float2 S[];
    const int tid = threadIdx.x;
    const int c = blockIdx.x;
    const int dbase = c << 1;
    const float* tp = T + dbase;

    // stage 1 (L=8192) fused with global load (full 8 inputs)
    {
        float2 a0 = *(const float2*)(tp + (size_t)(tid       ) * 512);
        float2 a1 = *(const float2*)(tp + (size_t)(tid + 1024) * 512);
        float2 a2 = *(const float2*)(tp + (size_t)(tid + 2048) * 512);
        float2 a3 = *(const float2*)(tp + (size_t)(tid + 3072) * 512);
        float2 a4 = *(const float2*)(tp + (size_t)(tid + 4096) * 512);
        float2 a5 = *(const float2*)(tp + (size_t)(tid + 5120) * 512);
        float2 a6 = *(const float2*)(tp + (size_t)(tid + 6144) * 512);
        float2 a7 = *(const float2*)(tp + (size_t)(tid + 7168) * 512);
        dft8_fwd(a0,a1,a2,a3,a4,a5,a6,a7);
        float sn, cs;
        __sincosf(-TWO_PI * (float)tid / 8192.0f, &sn, &cs);
        float2 w1 = make_float2(cs, sn);
        S[PAD(tid)] = a0;
        float2 w = w1;
        S[PAD(tid + 1024)] = cmul(a1, w); w = cmul(w, w1);
        S[PAD(tid + 2048)] = cmul(a2, w); w = cmul(w, w1);
        S[PAD(tid + 3072)] = cmul(a3, w); w = cmul(w, w1);
        S[PAD(tid + 4096)] = cmul(a4, w); w = cmul(w, w1);
        S[PAD(tid + 5120)] = cmul(a5, w); w = cmul(w, w1);
        S[PAD(tid + 6144)] = cmul(a6, w); w = cmul(w, w1);
        S[PAD(tid + 7168)] = cmul(a7, w);
    }
    __syncthreads();
    fwd_stage<7>(S, tid); __syncthreads();
    fwd_stage<4>(S, tid); __syncthreads();
    fwd_stage<1>(S, tid); __syncthreads();

    // separation (with fwd-r2 folded into reads), store Td,Te scaled by 0.5/N
    const float sc = 0.5f / (float)NFFT;
    float4* tb = Tsep + (size_t)c * NFFT;
    #pragma unroll
    for (int it = 0; it < 4; ++it) {
        int u = tid + (it << 10);
        int K = rev8_12(u);
        int v = rev8_12((4096 - K) & 4095);
        float2 V0 = S[PAD(2*u)], V1 = S[PAD(2*u + 1)];
        float2 Za = cadd(V0, V1), Zb = csub(V0, V1);   // freqs K, K+4096
        float2 Zc, Zd;
        if (u == 0) { Zc = Zb; Zd = Za; }              // k=0 / k=4096 self-paired
        else {
            float2 U0 = S[PAD(2*v)], U1 = S[PAD(2*v + 1)];
            Zc = cadd(U0, U1); Zd = csub(U0, U1);      // freqs 4096-K, 8192-K
        }
        tb[2*u]     = make_float4((Za.x + Zd.x) * sc, (Za.y - Zd.y) * sc,
                                  (Za.y + Zd.y) * sc, (Zd.x - Za.x) * sc);
        tb[2*u + 1] = make_float4((Zb.x + Zc.x) * sc, (Zb.y - Zc.y) * sc,
                                  (Zb.y + Zc.y) * sc, (Zc.x - Zb.x) * sc);
    }
}

// ---------------- main conv: 1024 blocks ----------------
__global__ __launch_bounds__(NTHR, 8) void fftconv4(
    const float* __restrict__ X, const float4* __restrict__ Tsep,
    float* __restrict__ O)
{
    extern __shared__ float2 S[];
    const int tid = threadIdx.x;

    int h = blockIdx.x;
    int Xc = h & 7, sl = h >> 3;
    int lbid = ((sl >> 3) << 6) | (Xc << 3) | (sl & 7);   // XCD-aware, bijective
    const int b = lbid >> 8;
    const int c = lbid & 255;
    const int dbase = c << 1;
    const float* xp = X + (size_t)b * 4096 * 512 + dbase;

    // stage 1 (L=8192) fused with load; inputs 4..7 are zero-pad
    {
        float2 a0 = *(const float2*)(xp + (size_t)(tid       ) * 512);
        float2 a1 = *(const float2*)(xp + (size_t)(tid + 1024) * 512);
        float2 a2 = *(const float2*)(xp + (size_t)(tid + 2048) * 512);
        float2 a3 = *(const float2*)(xp + (size_t)(tid + 3072) * 512);
        // y_{2r} = DFT4(a0..a3)_r ; y_{2r+1} = DFT4(a0, a1 w8, a2 w8^2, a3 w8^3)_r
        float2 s02 = cadd(a0,a2), d02 = csub(a0,a2), s13 = cadd(a1,a3), d13 = csub(a1,a3);
        float2 F0 = cadd(s02,s13), F2 = csub(s02,s13);
        float2 F1 = cadd(d02, mulnegi(d13)), F3 = csub(d02, mulnegi(d13));
        float2 g1 = mulw81(a1), g2 = mulnegi(a2), g3 = mulw83(a3);
        float2 gs02 = cadd(a0,g2), gd02 = csub(a0,g2), gs13 = cadd(g1,g3), gd13 = csub(g1,g3);
        float2 G0 = cadd(gs02,gs13), G2 = csub(gs02,gs13);
        float2 G1 = cadd(gd02, mulnegi(gd13)), G3 = csub(gd02, mulnegi(gd13));
        float sn, cs;
        __sincosf(-TWO_PI * (float)tid / 8192.0f, &sn, &cs);
        float2 w1 = make_float2(cs, sn);
        S[PAD(tid)] = F0;
        float2 w = w1;
        S[PAD(tid + 1024)] = cmul(G0, w); w = cmul(w, w1);
        S[PAD(tid + 2048)] = cmul(F1, w); w = cmul(w, w1);
        S[PAD(tid + 3072)] = cmul(G1, w); w = cmul(w, w1);
        S[PAD(tid + 4096)] = cmul(F2, w); w = cmul(w, w1);
        S[PAD(tid + 5120)] = cmul(G2, w); w = cmul(w, w1);
        S[PAD(tid + 6144)] = cmul(F3, w); w = cmul(w, w1);
        S[PAD(tid + 7168)] = cmul(G3, w);
    }
    __syncthreads();
    fwd_stage<7>(S, tid); __syncthreads();
    fwd_stage<4>(S, tid); __syncthreads();
    fwd_stage<1>(S, tid); __syncthreads();

    // fused: fwd-r2 + separation + spectral multiply + inv-r2 (regs across 1 barrier)
    const float4* tb = Tsep + (size_t)c * NFFT;
    float2 Wr[8];
    #pragma unroll
    for (int it = 0; it < 4; ++it) {
        int u = tid + (it << 10);
        int K = rev8_12(u);
        int v = rev8_12((4096 - K) & 4095);
        float2 V0 = S[PAD(2*u)], V1 = S[PAD(2*u + 1)];
        float2 Za = cadd(V0, V1), Zb = csub(V0, V1);
        float2 Zc, Zd;
        if (u == 0) { Zc = Zb; Zd = Za; }
        else {
            float2 U0 = S[PAD(2*v)], U1 = S[PAD(2*v + 1)];
            Zc = cadd(U0, U1); Zd = csub(U0, U1);
        }
        float4 t0 = tb[2*u], t1 = tb[2*u + 1];
        // freq K (slot 2u): Z = Za, conj-partner Zd
        float2 Xd = make_float2((Za.x + Zd.x) * 0.5f, (Za.y - Zd.y) * 0.5f);
        float2 Xe = make_float2((Za.y + Zd.y) * 0.5f, (Zd.x - Za.x) * 0.5f);
        float2 A0 = cmul(Xd, make_float2(t0.x, t0.y));
        float2 B0 = cmul(Xe, make_float2(t0.z, t0.w));
        float2 Q0 = make_float2(A0.x - B0.y, A0.y + B0.x);   // A0 + i*B0
        // freq K+4096 (slot 2u+1): Z = Zb, conj-partner Zc
        float2 Yd = make_float2((Zb.x + Zc.x) * 0.5f, (Zb.y - Zc.y) * 0.5f);
        float2 Ye = make_float2((Zb.y + Zc.y) * 0.5f, (Zc.x - Zb.x) * 0.5f);
        float2 A1 = cmul(Yd, make_float2(t1.x, t1.y));
        float2 B1 = cmul(Ye, make_float2(t1.z, t1.w));
        float2 Q1 = make_float2(A1.x - B1.y, A1.y + B1.x);
        Wr[2*it]     = cadd(Q0, Q1);                         // inv-r2 folded
        Wr[2*it + 1] = csub(Q0, Q1);
    }
    __syncthreads();
    #pragma unroll
    for (int it = 0; it < 4; ++it) {
        int u = tid + (it << 10);
        S[PAD(2*u)]     = Wr[2*it];
        S[PAD(2*u + 1)] = Wr[2*it + 1];
    }
    __syncthreads();

    inv_stage<1>(S, tid); __syncthreads();
    inv_stage<4>(S, tid); __syncthreads();
    inv_stage<7>(S, tid); __syncthreads();

    // final inv stage (L=8192) fused with store; only time outputs j=0..3 kept
    {
        float sn, cs;
        __sincosf(TWO_PI * (float)tid / 8192.0f, &sn, &cs);
        float2 w1 = make_float2(cs, sn);
        float2 z0 = S[PAD(tid)];
        float2 w = w1;
        float2 z1 = cmul(S[PAD(tid + 1024)], w); w = cmul(w, w1);
        float2 z2 = cmul(S[PAD(tid + 2048)], w); w = cmul(w, w1);
        float2 z3 = cmul(S[PAD(tid + 3072)], w); w = cmul(w, w1);
        float2 z4 = cmul(S[PAD(tid + 4096)], w); w = cmul(w, w1);
        float2 z5 = cmul(S[PAD(tid + 5120)], w); w = cmul(w, w1);
        float2 z6 = cmul(S[PAD(tid + 6144)], w); w = cmul(w, w1);
        float2 z7 = cmul(S[PAD(tid + 7168)], w);
        float2 s02 = cadd(z0,z4), d02 = csub(z0,z4), s13 = cadd(z2,z6), d13 = csub(z2,z6);
        float2 P0 = cadd(s02,s13), P2 = csub(s02,s13);
        float2 P1 = cadd(d02, mulposi(d13)), P3 = csub(d02, mulposi(d13));
        float2 t02 = cadd(z1,z5), u02 = csub(z1,z5), t13 = cadd(z3,z7), u13 = csub(z3,z7);
        float2 Q0 = cadd(t02,t13), Q2 = csub(t02,t13);
        float2 Q1 = cadd(u02, mulposi(u13)), Q3 = csub(u02, mulposi(u13));
        float* op = O + (size_t)b * 4096 * 512 + dbase;
        *(float2*)(op + (size_t)(tid       ) * 512) = cadd(P0, Q0);
        *(float2*)(op + (size_t)(tid + 1024) * 512) = cadd(P1, mulv81(Q1));
        *(float2*)(op + (size_t)(tid + 2048) * 512) = cadd(P2, mulposi(Q2));
        *(float2*)(op + (size_t)(tid + 3072) * 512) = cadd(P3, mulv83(Q3));
    }
}

extern "C" void kernel_launch(void* const* d_in, const int* in_sizes, int n_in,
                              void* d_out, int out_size, void* d_ws, size_t ws_size,
                              hipStream_t stream)
{
    const float* x = (const float*)d_in[0];   // (4, 4096, 512)
    const float* t = (const float*)d_in[1];   // (8192, 512)
    float* out = (float*)d_out;               // (4, 4096, 512)
    float4* tsep = (float4*)d_ws;             // 256*8192*16 B = 32 MB

    const int lds = (int)(LDS_ELEMS * sizeof(float2));   // 69632
    (void)hipFuncSetAttribute((const void*)tsep_k,
                              hipFuncAttributeMaxDynamicSharedMemorySize, lds);
    (void)hipFuncSetAttribute((const void*)fftconv4,
                              hipFuncAttributeMaxDynamicSharedMemorySize, lds);

    tsep_k<<<256, NTHR, lds, stream>>>(t, tsep);
    fftconv4<<<1024, NTHR, lds, stream>>>(x, tsep, out);
}

// Round 5
// 102.208 us; speedup vs baseline: 1.9139x; 1.1530x over previous
//
#include <hip/hip_runtime.h>
#include <math.h>

// Round 5: dual-pair blocks. Each block owns 4 channels (2 complex-packed pairs),
// two LDS buffers (139 KB, 1 block/CU, 16 waves). float4 global I/O, shared
// twiddles (1 sincos + one w^1..w^7 chain serves 2 butterflies), 2 butterflies
// per thread per stage for ILP. __launch_bounds__(1024,4) -> VGPR cap 128 so the
// compiler can hoist LDS reads (round-4's 32-VGPR starvation was the stall).
// FFT: register radix-8, 8192 = 8^4 * 2; slot perm = octal digit reversal.

#define NFFT 8192
#define NTHR 1024
#define PAD(i) ((i) + ((i) >> 4))
#define LDS_ELEMS (NFFT + (NFFT >> 4))          // 8704 float2 = 69632 B per buffer
#define TWO_PI 6.28318530717958647692f
#define RSQRT2 0.70710678118654752440f

__device__ __forceinline__ float2 cadd(float2 a, float2 b){ return make_float2(a.x+b.x, a.y+b.y); }
__device__ __forceinline__ float2 csub(float2 a, float2 b){ return make_float2(a.x-b.x, a.y-b.y); }
__device__ __forceinline__ float2 cmul(float2 a, float2 b){ return make_float2(a.x*b.x - a.y*b.y, a.x*b.y + a.y*b.x); }
__device__ __forceinline__ float2 mulnegi(float2 a){ return make_float2(a.y, -a.x); }   // * (-i)
__device__ __forceinline__ float2 mulposi(float2 a){ return make_float2(-a.y, a.x); }   // * (+i)
__device__ __forceinline__ float2 mulw81(float2 z){ return make_float2(RSQRT2*(z.x+z.y), RSQRT2*(z.y-z.x)); }  // * e^{-i pi/4}
__device__ __forceinline__ float2 mulw83(float2 z){ return make_float2(RSQRT2*(z.y-z.x), -RSQRT2*(z.x+z.y)); } // * e^{-i 3pi/4}
__device__ __forceinline__ float2 mulv81(float2 z){ return make_float2(RSQRT2*(z.x-z.y), RSQRT2*(z.x+z.y)); }  // * e^{+i pi/4}
__device__ __forceinline__ float2 mulv83(float2 z){ return make_float2(-RSQRT2*(z.x+z.y), RSQRT2*(z.x-z.y)); } // * e^{+i 3pi/4}

__device__ __forceinline__ int rev8_12(int u) {   // 4-octal-digit reversal, involution
    return ((u & 7) << 9) | (((u >> 3) & 7) << 6) | (((u >> 6) & 7) << 3) | ((u >> 9) & 7);
}

__device__ __forceinline__ void dft8_fwd(float2& a0, float2& a1, float2& a2, float2& a3,
                                         float2& a4, float2& a5, float2& a6, float2& a7) {
    float2 s02 = cadd(a0,a4), d02 = csub(a0,a4), s13 = cadd(a2,a6), d13 = csub(a2,a6);
    float2 E0 = cadd(s02,s13), E2 = csub(s02,s13);
    float2 E1 = cadd(d02, mulnegi(d13)), E3 = csub(d02, mulnegi(d13));
    float2 t02 = cadd(a1,a5), u02 = csub(a1,a5), t13 = cadd(a3,a7), u13 = csub(a3,a7);
    float2 O0 = cadd(t02,t13), O2 = csub(t02,t13);
    float2 O1 = cadd(u02, mulnegi(u13)), O3 = csub(u02, mulnegi(u13));
    float2 W1 = mulw81(O1), W2 = mulnegi(O2), W3 = mulw83(O3);
    a0 = cadd(E0,O0); a4 = csub(E0,O0);
    a1 = cadd(E1,W1); a5 = csub(E1,W1);
    a2 = cadd(E2,W2); a6 = csub(E2,W2);
    a3 = cadd(E3,W3); a7 = csub(E3,W3);
}

__device__ __forceinline__ void dft8_inv(float2& a0, float2& a1, float2& a2, float2& a3,
                                         float2& a4, float2& a5, float2& a6, float2& a7) {
    float2 s02 = cadd(a0,a4), d02 = csub(a0,a4), s13 = cadd(a2,a6), d13 = csub(a2,a6);
    float2 P0 = cadd(s02,s13), P2 = csub(s02,s13);
    float2 P1 = cadd(d02, mulposi(d13)), P3 = csub(d02, mulposi(d13));
    float2 t02 = cadd(a1,a5), u02 = csub(a1,a5), t13 = cadd(a3,a7), u13 = csub(a3,a7);
    float2 Q0 = cadd(t02,t13), Q2 = csub(t02,t13);
    float2 Q1 = cadd(u02, mulposi(u13)), Q3 = csub(u02, mulposi(u13));
    float2 W1 = mulv81(Q1), W2 = mulposi(Q2), W3 = mulv83(Q3);
    a0 = cadd(P0,Q0); a4 = csub(P0,Q0);
    a1 = cadd(P1,W1); a5 = csub(P1,W1);
    a2 = cadd(P2,W2); a6 = csub(P2,W2);
    a3 = cadd(P3,W3); a7 = csub(P3,W3);
}

// one radix-8 fwd butterfly on buffer S (indices/twiddles from caller)
__device__ __forceinline__ void fwd_one(float2* __restrict__ S,
    int i0,int i1,int i2,int i3,int i4,int i5,int i6,int i7,
    float2 w1,float2 w2,float2 w3,float2 w4,float2 w5,float2 w6,float2 w7) {
    float2 a0=S[i0],a1=S[i1],a2=S[i2],a3=S[i3],a4=S[i4],a5=S[i5],a6=S[i6],a7=S[i7];
    dft8_fwd(a0,a1,a2,a3,a4,a5,a6,a7);
    S[i0]=a0;           S[i1]=cmul(a1,w1); S[i2]=cmul(a2,w2); S[i3]=cmul(a3,w3);
    S[i4]=cmul(a4,w4);  S[i5]=cmul(a5,w5); S[i6]=cmul(a6,w6); S[i7]=cmul(a7,w7);
}

__device__ __forceinline__ void inv_one(float2* __restrict__ S,
    int i0,int i1,int i2,int i3,int i4,int i5,int i6,int i7,
    float2 w1,float2 w2,float2 w3,float2 w4,float2 w5,float2 w6,float2 w7) {
    float2 a0=S[i0];
    float2 a1=cmul(S[i1],w1), a2=cmul(S[i2],w2), a3=cmul(S[i3],w3), a4=cmul(S[i4],w4),
           a5=cmul(S[i5],w5), a6=cmul(S[i6],w6), a7=cmul(S[i7],w7);
    dft8_inv(a0,a1,a2,a3,a4,a5,a6,a7);
    S[i0]=a0; S[i1]=a1; S[i2]=a2; S[i3]=a3; S[i4]=a4; S[i5]=a5; S[i6]=a6; S[i7]=a7;
}

template<int LQ>
__device__ __forceinline__ void fwd_stage2(float2* __restrict__ S0, float2* __restrict__ S1, int tid) {
    const int q = 1 << LQ;
    const int m = tid & (q - 1);
    const int B = ((tid >> LQ) << (LQ + 3)) + m;
    const int i0=PAD(B),i1=PAD(B+q),i2=PAD(B+2*q),i3=PAD(B+3*q),
              i4=PAD(B+4*q),i5=PAD(B+5*q),i6=PAD(B+6*q),i7=PAD(B+7*q);
    float sn, cs;
    __sincosf(-TWO_PI * (float)m / (float)(q << 3), &sn, &cs);
    float2 w1 = make_float2(cs, sn);
    float2 w2 = cmul(w1,w1), w3 = cmul(w2,w1), w4 = cmul(w2,w2),
           w5 = cmul(w4,w1), w6 = cmul(w4,w2), w7 = cmul(w4,w3);
    fwd_one(S0,i0,i1,i2,i3,i4,i5,i6,i7,w1,w2,w3,w4,w5,w6,w7);
    fwd_one(S1,i0,i1,i2,i3,i4,i5,i6,i7,w1,w2,w3,w4,w5,w6,w7);
}

template<int LQ>
__device__ __forceinline__ void inv_stage2(float2* __restrict__ S0, float2* __restrict__ S1, int tid) {
    const int q = 1 << LQ;
    const int m = tid & (q - 1);
    const int B = ((tid >> LQ) << (LQ + 3)) + m;
    const int i0=PAD(B),i1=PAD(B+q),i2=PAD(B+2*q),i3=PAD(B+3*q),
              i4=PAD(B+4*q),i5=PAD(B+5*q),i6=PAD(B+6*q),i7=PAD(B+7*q);
    float sn, cs;
    __sincosf(TWO_PI * (float)m / (float)(q << 3), &sn, &cs);
    float2 w1 = make_float2(cs, sn);
    float2 w2 = cmul(w1,w1), w3 = cmul(w2,w1), w4 = cmul(w2,w2),
           w5 = cmul(w4,w1), w6 = cmul(w4,w2), w7 = cmul(w4,w3);
    inv_one(S0,i0,i1,i2,i3,i4,i5,i6,i7,w1,w2,w3,w4,w5,w6,w7);
    inv_one(S1,i0,i1,i2,i3,i4,i5,i6,i7,w1,w2,w3,w4,w5,w6,w7);
}

// fwd-r2 + conj-symmetry separation + Tsep mul + inv-r2, regs across 1 barrier
__device__ __forceinline__ void sep_pass(float2* __restrict__ S,
                                         const float4* __restrict__ tb, int tid) {
    float2 Wr[8];
    #pragma unroll
    for (int it = 0; it < 4; ++it) {
        int u = tid + (it << 10);
        int K = rev8_12(u);
        int v = rev8_12((4096 - K) & 4095);
        float2 V0 = S[PAD(2*u)], V1 = S[PAD(2*u + 1)];
        float2 Za = cadd(V0, V1), Zb = csub(V0, V1);
        float2 Zc, Zd;
        if (u == 0) { Zc = Zb; Zd = Za; }
        else {
            float2 U0 = S[PAD(2*v)], U1 = S[PAD(2*v + 1)];
            Zc = cadd(U0, U1); Zd = csub(U0, U1);
        }
        float4 t0 = tb[2*u], t1 = tb[2*u + 1];
        float2 Xd = make_float2((Za.x + Zd.x) * 0.5f, (Za.y - Zd.y) * 0.5f);
        float2 Xe = make_float2((Za.y + Zd.y) * 0.5f, (Zd.x - Za.x) * 0.5f);
        float2 A0 = cmul(Xd, make_float2(t0.x, t0.y));
        float2 B0 = cmul(Xe, make_float2(t0.z, t0.w));
        float2 Q0 = make_float2(A0.x - B0.y, A0.y + B0.x);
        float2 Yd = make_float2((Zb.x + Zc.x) * 0.5f, (Zb.y - Zc.y) * 0.5f);
        float2 Ye = make_float2((Zb.y + Zc.y) * 0.5f, (Zc.x - Zb.x) * 0.5f);
        float2 A1 = cmul(Yd, make_float2(t1.x, t1.y));
        float2 B1 = cmul(Ye, make_float2(t1.z, t1.w));
        float2 Q1 = make_float2(A1.x - B1.y, A1.y + B1.x);
        Wr[2*it]     = cadd(Q0, Q1);
        Wr[2*it + 1] = csub(Q0, Q1);
    }
    __syncthreads();
    #pragma unroll
    for (int it = 0; it < 4; ++it) {
        int u = tid + (it << 10);
        S[PAD(2*u)]     = Wr[2*it];
        S[PAD(2*u + 1)] = Wr[2*it + 1];
    }
}

// x stage 1 (L=8192) with inputs 4..7 zero; write to S with twiddle chain
__device__ __forceinline__ void xstage1(float2 a0, float2 a1, float2 a2, float2 a3,
    float2* __restrict__ S, int tid,
    float2 w1,float2 w2,float2 w3,float2 w4,float2 w5,float2 w6,float2 w7) {
    float2 s02 = cadd(a0,a2), d02 = csub(a0,a2), s13 = cadd(a1,a3), d13 = csub(a1,a3);
    float2 F0 = cadd(s02,s13), F2 = csub(s02,s13);
    float2 F1 = cadd(d02, mulnegi(d13)), F3 = csub(d02, mulnegi(d13));
    float2 g1 = mulw81(a1), g2 = mulnegi(a2), g3 = mulw83(a3);
    float2 gs02 = cadd(a0,g2), gd02 = csub(a0,g2), gs13 = cadd(g1,g3), gd13 = csub(g1,g3);
    float2 G0 = cadd(gs02,gs13), G2 = csub(gs02,gs13);
    float2 G1 = cadd(gd02, mulnegi(gd13)), G3 = csub(gd02, mulnegi(gd13));
    S[PAD(tid)]        = F0;
    S[PAD(tid + 1024)] = cmul(G0, w1);
    S[PAD(tid + 2048)] = cmul(F1, w2);
    S[PAD(tid + 3072)] = cmul(G1, w3);
    S[PAD(tid + 4096)] = cmul(F2, w4);
    S[PAD(tid + 5120)] = cmul(G2, w5);
    S[PAD(tid + 6144)] = cmul(F3, w6);
    S[PAD(tid + 7168)] = cmul(G3, w7);
}

// t stage 1 (full 8 inputs)
__device__ __forceinline__ void tstage1(float2 a0, float2 a1, float2 a2, float2 a3,
    float2 a4, float2 a5, float2 a6, float2 a7, float2* __restrict__ S, int tid,
    float2 w1,float2 w2,float2 w3,float2 w4,float2 w5,float2 w6,float2 w7) {
    dft8_fwd(a0,a1,a2,a3,a4,a5,a6,a7);
    S[PAD(tid)]        = a0;
    S[PAD(tid + 1024)] = cmul(a1, w1);
    S[PAD(tid + 2048)] = cmul(a2, w2);
    S[PAD(tid + 3072)] = cmul(a3, w3);
    S[PAD(tid + 4096)] = cmul(a4, w4);
    S[PAD(tid + 5120)] = cmul(a5, w5);
    S[PAD(tid + 6144)] = cmul(a6, w6);
    S[PAD(tid + 7168)] = cmul(a7, w7);
}

// final inverse stage (L=8192): compute time outputs j=0..3 only
__device__ __forceinline__ void inv_final(const float2* __restrict__ S, int tid,
    float2 w1,float2 w2,float2 w3,float2 w4,float2 w5,float2 w6,float2 w7,
    float2& r0, float2& r1, float2& r2, float2& r3) {
    float2 z0 = S[PAD(tid)];
    float2 z1 = cmul(S[PAD(tid + 1024)], w1);
    float2 z2 = cmul(S[PAD(tid + 2048)], w2);
    float2 z3 = cmul(S[PAD(tid + 3072)], w3);
    float2 z4 = cmul(S[PAD(tid + 4096)], w4);
    float2 z5 = cmul(S[PAD(tid + 5120)], w5);
    float2 z6 = cmul(S[PAD(tid + 6144)], w6);
    float2 z7 = cmul(S[PAD(tid + 7168)], w7);
    float2 s02 = cadd(z0,z4), d02 = csub(z0,z4), s13 = cadd(z2,z6), d13 = csub(z2,z6);
    float2 P0 = cadd(s02,s13), P2 = csub(s02,s13);
    float2 P1 = cadd(d02, mulposi(d13)), P3 = csub(d02, mulposi(d13));
    float2 t02 = cadd(z1,z5), u02 = csub(z1,z5), t13 = cadd(z3,z7), u13 = csub(z3,z7);
    float2 Q0 = cadd(t02,t13), Q2 = csub(t02,t13);
    float2 Q1 = cadd(u02, mulposi(u13)), Q3 = csub(u02, mulposi(u13));
    r0 = cadd(P0, Q0);
    r1 = cadd(P1, mulv81(Q1));
    r2 = cadd(P2, mulposi(Q2));
    r3 = cadd(P3, mulv83(Q3));
}

// T-spectrum separation + store for one buffer
__device__ __forceinline__ void tsep_tail(const float2* __restrict__ S,
                                          float4* __restrict__ tb, int tid) {
    const float sc = 0.5f / (float)NFFT;
    #pragma unroll
    for (int it = 0; it < 4; ++it) {
        int u = tid + (it << 10);
        int K = rev8_12(u);
        int v = rev8_12((4096 - K) & 4095);
        float2 V0 = S[PAD(2*u)], V1 = S[PAD(2*u + 1)];
        float2 Za = cadd(V0, V1), Zb = csub(V0, V1);
        float2 Zc, Zd;
        if (u == 0) { Zc = Zb; Zd = Za; }
        else {
            float2 U0 = S[PAD(2*v)], U1 = S[PAD(2*v + 1)];
            Zc = cadd(U0, U1); Zd = csub(U0, U1);
        }
        tb[2*u]     = make_float4((Za.x + Zd.x) * sc, (Za.y - Zd.y) * sc,
                                  (Za.y + Zd.y) * sc, (Zd.x - Za.x) * sc);
        tb[2*u + 1] = make_float4((Zb.x + Zc.x) * sc, (Zb.y - Zc.y) * sc,
                                  (Zb.y + Zc.y) * sc, (Zc.x - Zb.x) * sc);
    }
}

// ---------------- T precompute: 128 blocks, 4 channels each ----------------
__global__ __launch_bounds__(NTHR, 4) void tsep2_k(
    const float* __restrict__ T, float4* __restrict__ Tsep)
{
    extern __shared__ float2 L[];
    float2* S0 = L;
    float2* S1 = L + LDS_ELEMS;
    const int tid = threadIdx.x;
    const int g = blockIdx.x;              // [0,128)
    const float* tp = T + (g << 2);

    float4 l0 = *(const float4*)(tp + (size_t)(tid       ) * 512);
    float4 l1 = *(const float4*)(tp + (size_t)(tid + 1024) * 512);
    float4 l2 = *(const float4*)(tp + (size_t)(tid + 2048) * 512);
    float4 l3 = *(const float4*)(tp + (size_t)(tid + 3072) * 512);
    float4 l4 = *(const float4*)(tp + (size_t)(tid + 4096) * 512);
    float4 l5 = *(const float4*)(tp + (size_t)(tid + 5120) * 512);
    float4 l6 = *(const float4*)(tp + (size_t)(tid + 6144) * 512);
    float4 l7 = *(const float4*)(tp + (size_t)(tid + 7168) * 512);
    {
        float sn, cs;
        __sincosf(-TWO_PI * (float)tid / 8192.0f, &sn, &cs);
        float2 w1 = make_float2(cs, sn);
        float2 w2 = cmul(w1,w1), w3 = cmul(w2,w1), w4 = cmul(w2,w2),
               w5 = cmul(w4,w1), w6 = cmul(w4,w2), w7 = cmul(w4,w3);
        tstage1(make_float2(l0.x,l0.y), make_float2(l1.x,l1.y), make_float2(l2.x,l2.y),
                make_float2(l3.x,l3.y), make_float2(l4.x,l4.y), make_float2(l5.x,l5.y),
                make_float2(l6.x,l6.y), make_float2(l7.x,l7.y), S0, tid,
                w1,w2,w3,w4,w5,w6,w7);
        tstage1(make_float2(l0.z,l0.w), make_float2(l1.z,l1.w), make_float2(l2.z,l2.w),
                make_float2(l3.z,l3.w), make_float2(l4.z,l4.w), make_float2(l5.z,l5.w),
                make_float2(l6.z,l6.w), make_float2(l7.z,l7.w), S1, tid,
                w1,w2,w3,w4,w5,w6,w7);
    }
    __syncthreads();
    fwd_stage2<7>(S0, S1, tid); __syncthreads();
    fwd_stage2<4>(S0, S1, tid); __syncthreads();
    fwd_stage2<1>(S0, S1, tid); __syncthreads();

    tsep_tail(S0, Tsep + (size_t)(2*g)     * NFFT, tid);
    tsep_tail(S1, Tsep + (size_t)(2*g + 1) * NFFT, tid);
}

// ---------------- main conv: 512 blocks, 4 channels each ----------------
__global__ __launch_bounds__(NTHR, 4) void fftconv5(
    const float* __restrict__ X, const float4* __restrict__ Tsep,
    float* __restrict__ O)
{
    extern __shared__ float2 L[];
    float2* S0 = L;
    float2* S1 = L + LDS_ELEMS;
    const int tid = threadIdx.x;

    // XCD swizzle: 4 consecutive-g blocks (sharing 64B lines) per XCD
    int h = blockIdx.x;                    // [0,512)
    int xcd = h & 7, sl = h >> 3;
    int lbid = ((sl >> 2) << 5) | (xcd << 2) | (sl & 3);   // bijective on [0,512)
    const int b = lbid >> 7;
    const int g = lbid & 127;
    const float* xp = X + (size_t)b * 4096 * 512 + (g << 2);

    float4 l0 = *(const float4*)(xp + (size_t)(tid       ) * 512);
    float4 l1 = *(const float4*)(xp + (size_t)(tid + 1024) * 512);
    float4 l2 = *(const float4*)(xp + (size_t)(tid + 2048) * 512);
    float4 l3 = *(const float4*)(xp + (size_t)(tid + 3072) * 512);
    {
        float sn, cs;
        __sincosf(-TWO_PI * (float)tid / 8192.0f, &sn, &cs);
        float2 w1 = make_float2(cs, sn);
        float2 w2 = cmul(w1,w1), w3 = cmul(w2,w1), w4 = cmul(w2,w2),
               w5 = cmul(w4,w1), w6 = cmul(w4,w2), w7 = cmul(w4,w3);
        xstage1(make_float2(l0.x,l0.y), make_float2(l1.x,l1.y),
                make_float2(l2.x,l2.y), make_float2(l3.x,l3.y), S0, tid,
                w1,w2,w3,w4,w5,w6,w7);
        xstage1(make_float2(l0.z,l0.w), make_float2(l1.z,l1.w),
                make_float2(l2.z,l2.w), make_float2(l3.z,l3.w), S1, tid,
                w1,w2,w3,w4,w5,w6,w7);
    }
    __syncthreads();
    fwd_stage2<7>(S0, S1, tid); __syncthreads();
    fwd_stage2<4>(S0, S1, tid); __syncthreads();
    fwd_stage2<1>(S0, S1, tid); __syncthreads();

    sep_pass(S0, Tsep + (size_t)(2*g)     * NFFT, tid);   // internal barrier
    sep_pass(S1, Tsep + (size_t)(2*g + 1) * NFFT, tid);   // internal barrier
    __syncthreads();

    inv_stage2<1>(S0, S1, tid); __syncthreads();
    inv_stage2<4>(S0, S1, tid); __syncthreads();
    inv_stage2<7>(S0, S1, tid); __syncthreads();

    {
        float sn, cs;
        __sincosf(TWO_PI * (float)tid / 8192.0f, &sn, &cs);
        float2 w1 = make_float2(cs, sn);
        float2 w2 = cmul(w1,w1), w3 = cmul(w2,w1), w4 = cmul(w2,w2),
               w5 = cmul(w4,w1), w6 = cmul(w4,w2), w7 = cmul(w4,w3);
        float2 p0,p1,p2,p3, q0,q1,q2,q3;
        inv_final(S0, tid, w1,w2,w3,w4,w5,w6,w7, p0,p1,p2,p3);
        inv_final(S1, tid, w1,w2,w3,w4,w5,w6,w7, q0,q1,q2,q3);
        float* op = O + (size_t)b * 4096 * 512 + (g << 2);
        *(float4*)(op + (size_t)(tid       ) * 512) = make_float4(p0.x,p0.y,q0.x,q0.y);
        *(float4*)(op + (size_t)(tid + 1024) * 512) = make_float4(p1.x,p1.y,q1.x,q1.y);
        *(float4*)(op + (size_t)(tid + 2048) * 512) = make_float4(p2.x,p2.y,q2.x,q2.y);
        *(float4*)(op + (size_t)(tid + 3072) * 512) = make_float4(p3.x,p3.y,q3.x,q3.y);
    }
}

extern "C" void kernel_launch(void* const* d_in, const int* in_sizes, int n_in,
                              void* d_out, int out_size, void* d_ws, size_t ws_size,
                              hipStream_t stream)
{
    const float* x = (const float*)d_in[0];   // (4, 4096, 512)
    const float* t = (const float*)d_in[1];   // (8192, 512)
    float* out = (float*)d_out;               // (4, 4096, 512)
    float4* tsep = (float4*)d_ws;             // 256*8192*16 B = 32 MB

    const int lds = (int)(2 * LDS_ELEMS * sizeof(float2));   // 139264
    (void)hipFuncSetAttribute((const void*)tsep2_k,
                              hipFuncAttributeMaxDynamicSharedMemorySize, lds);
    (void)hipFuncSetAttribute((const void*)fftconv5,
                              hipFuncAttributeMaxDynamicSharedMemorySize, lds);

    tsep2_k<<<128, NTHR, lds, stream>>>(t, tsep);
    fftconv5<<<512, NTHR, lds, stream>>>(x, tsep, out);
}